// Round 1
// baseline (774.277 us; speedup 1.0000x reference)
//
#include <hip/hip_runtime.h>
#include <hip/hip_bf16.h>

typedef __attribute__((ext_vector_type(8))) __bf16 bf16x8;
typedef __attribute__((ext_vector_type(4))) float f32x4;
typedef __attribute__((ext_vector_type(4))) unsigned short us4;

__device__ __forceinline__ unsigned short f2bf(float f){
  union { float f; unsigned int u; } a; a.f = f;
  unsigned int r = 0x7fffu + ((a.u >> 16) & 1u);
  return (unsigned short)((a.u + r) >> 16);
}

__device__ __forceinline__ void gload_lds16(const unsigned short* g, void* l){
  __builtin_amdgcn_global_load_lds(
      (const __attribute__((address_space(1))) void*)g,
      (__attribute__((address_space(3))) void*)l, 16, 0, 0);
}

// ---------------- cast fp32 -> bf16 (vector4) ----------------
__global__ __launch_bounds__(256) void cast_kernel(const float* __restrict__ in,
                                                   unsigned short* __restrict__ out, int n4){
  int i = blockIdx.x * 256 + threadIdx.x;
  if (i >= n4) return;
  float4 v = ((const float4*)in)[i];
  us4 o; o.x = f2bf(v.x); o.y = f2bf(v.y); o.z = f2bf(v.z); o.w = f2bf(v.w);
  ((us4*)out)[i] = o;
}

// ---------------- modulation: y = silu(emb) @ w.T (3 matrices of 3072x1024) ----------------
__global__ __launch_bounds__(256) void modulation_kernel(const float* __restrict__ emb,
    const float* __restrict__ w0, const float* __restrict__ w1, const float* __restrict__ w2,
    float* __restrict__ out){
  int gw = blockIdx.x * 4 + (threadIdx.x >> 6);
  int lane = threadIdx.x & 63;
  int mat = gw / 3072, row = gw % 3072;
  const float* w = (mat == 0) ? w0 : (mat == 1 ? w1 : w2);
  float acc = 0.f;
  for (int i = lane; i < 1024; i += 64){
    float e = emb[i];
    float s = e / (1.f + expf(-e));
    acc += s * w[row * 1024 + i];
  }
  #pragma unroll
  for (int m = 32; m >= 1; m >>= 1) acc += __shfl_xor(acc, m, 64);
  if (lane == 0) out[mat * 3072 + row] = acc;
}

// ---------------- layernorm * (1+scale) + shift -> bf16 ----------------
__global__ __launch_bounds__(256) void ln_mod_kernel(const float* __restrict__ x,
    const float* __restrict__ mod, unsigned short* __restrict__ h){
  int row = blockIdx.x, t = threadIdx.x;
  const float* xr = x + (size_t)row * 1024;
  float4 v = ((const float4*)xr)[t];
  float s = v.x + v.y + v.z + v.w;
  #pragma unroll
  for (int m = 32; m >= 1; m >>= 1) s += __shfl_xor(s, m, 64);
  __shared__ float red[4], red2[4];
  int wid = t >> 6, lane = t & 63;
  if (lane == 0) red[wid] = s;
  __syncthreads();
  float mean = (red[0] + red[1] + red[2] + red[3]) * (1.f / 1024.f);
  float dx = v.x - mean, dy = v.y - mean, dz = v.z - mean, dw = v.w - mean;
  float s2 = dx*dx + dy*dy + dz*dz + dw*dw;
  #pragma unroll
  for (int m = 32; m >= 1; m >>= 1) s2 += __shfl_xor(s2, m, 64);
  if (lane == 0) red2[wid] = s2;
  __syncthreads();
  float var = (red2[0] + red2[1] + red2[2] + red2[3]) * (1.f / 1024.f);
  float rs = rsqrtf(var + 1e-6f);
  int c = t * 4;
  us4 o;
  o.x = f2bf(dx * rs * (1.f + mod[1024 + c    ]) + mod[c    ]);
  o.y = f2bf(dy * rs * (1.f + mod[1024 + c + 1]) + mod[c + 1]);
  o.z = f2bf(dz * rs * (1.f + mod[1024 + c + 2]) + mod[c + 2]);
  o.w = f2bf(dw * rs * (1.f + mod[1024 + c + 3]) + mod[c + 3]);
  ((us4*)(h + (size_t)row * 1024))[t] = o;
}

// ---------------- rmsnorm (*nw) + optional rope, fp32 [S][16][64] -> bf16 [16][S][64] ----------------
template<int ROPE>
__global__ __launch_bounds__(256) void qk_post_kernel(const float* __restrict__ qin,
    const float* __restrict__ nw, const float* __restrict__ rope,
    unsigned short* __restrict__ qout, int S){
  int gw = blockIdx.x * 4 + (threadIdx.x >> 6);
  int lane = threadIdx.x & 63;
  int s = gw >> 4, h = gw & 15;
  float v = qin[(size_t)s * 1024 + h * 64 + lane];
  float ss = v * v;
  #pragma unroll
  for (int m = 32; m >= 1; m >>= 1) ss += __shfl_xor(ss, m, 64);
  float val = v * rsqrtf(ss * (1.f / 64.f) + 1e-6f) * nw[lane];
  if (ROPE){
    float partner = __shfl_xor(val, 32, 64);
    float cs = rope[s * 64 + (lane & 31)];
    float sn = rope[s * 64 + 32 + (lane & 31)];
    val = (lane < 32) ? (val * cs - partner * sn) : (val * cs + partner * sn);
  }
  qout[((size_t)h * S + s) * 64 + lane] = f2bf(val);
}

// ---------------- GEMM: C[M,N] = A[M,K](bf16) * W[N,K](bf16)^T, fp32 acc ----------------
// 128x128 tile, BK=64, 4 waves 2x2, global_load_lds(16B) with XOR-swizzled source.
// EPI: 0 = store fp32; 2 = gelu(exact)->bf16; 3 = resid + gate[col]*acc -> fp32
template<int EPI>
__global__ __launch_bounds__(256) void gemm_bt_kernel(
    const unsigned short* __restrict__ A, const unsigned short* __restrict__ W,
    int M, int N, int K,
    float* __restrict__ outF, unsigned short* __restrict__ outB,
    const float* __restrict__ resid, const float* __restrict__ gate){
  __shared__ short As[128 * 64];
  __shared__ short Bs[128 * 64];
  const int t = threadIdx.x, wid = t >> 6, lane = t & 63;
  const int r = lane & 15, g = lane >> 4;
  const int brow = blockIdx.y * 128, bcol = blockIdx.x * 128;
  const int wr = wid >> 1, wc = wid & 1;
  f32x4 acc[4][4] = {};
  const int nkt = K >> 6;
  for (int kt = 0; kt < nkt; ++kt){
    const int k0 = kt << 6;
    #pragma unroll
    for (int i = 0; i < 4; i++){
      int chunk = wid * 4 + i;                 // 16 chunks of 8 rows
      int rowi = chunk * 8 + (lane >> 3);
      int lce = ((lane & 7) * 8) ^ ((rowi & 7) << 3);  // swizzled source column (elems)
      gload_lds16(A + (size_t)(brow + rowi) * K + k0 + lce, (void*)(As + chunk * 512));
      gload_lds16(W + (size_t)(bcol + rowi) * K + k0 + lce, (void*)(Bs + chunk * 512));
    }
    __syncthreads();
    #pragma unroll
    for (int kk = 0; kk < 2; kk++){
      bf16x8 af[4], bfr[4];
      #pragma unroll
      for (int m = 0; m < 4; m++){
        int ar = wr * 64 + m * 16 + r;
        af[m] = *(const bf16x8*)(As + ar * 64 + ((kk * 32 + g * 8) ^ ((ar & 7) << 3)));
      }
      #pragma unroll
      for (int n = 0; n < 4; n++){
        int br = wc * 64 + n * 16 + r;
        bfr[n] = *(const bf16x8*)(Bs + br * 64 + ((kk * 32 + g * 8) ^ ((br & 7) << 3)));
      }
      #pragma unroll
      for (int m = 0; m < 4; m++)
        #pragma unroll
        for (int n = 0; n < 4; n++)
          acc[m][n] = __builtin_amdgcn_mfma_f32_16x16x32_bf16(af[m], bfr[n], acc[m][n], 0, 0, 0);
    }
    __syncthreads();
  }
  #pragma unroll
  for (int m = 0; m < 4; m++){
    #pragma unroll
    for (int n = 0; n < 4; n++){
      int col = bcol + wc * 64 + n * 16 + r;
      #pragma unroll
      for (int j = 0; j < 4; j++){
        int rowj = brow + wr * 64 + m * 16 + g * 4 + j;
        float v = acc[m][n][j];
        if (EPI == 0){
          outF[(size_t)rowj * N + col] = v;
        } else if (EPI == 2){
          float gl = 0.5f * v * (1.f + erff(v * 0.70710678118654752f));
          outB[(size_t)rowj * N + col] = f2bf(gl);
        } else {
          outF[(size_t)rowj * N + col] = resid[(size_t)rowj * N + col] + gate[col] * v;
        }
      }
    }
  }
}

// ---------------- flash attention ----------------
// Q: bf16 [16][Sq][64], K: bf16 [16][Skv][64], V: fp32 [Skv][1024], Out: bf16 [Sq][1024]
// block = 4 waves, 64 q-rows (16/wave), KVBLK = 64.
__global__ __launch_bounds__(256) void attn_kernel(
    const unsigned short* __restrict__ Qb, const unsigned short* __restrict__ Kb,
    const float* __restrict__ Vf, unsigned short* __restrict__ Out,
    int Sq, int Skv){
  __shared__ short Ks[64 * 72];
  __shared__ short Vt[64 * 72];        // V transposed: Vt[d][k]
  __shared__ short Ps[4 * 16 * 72];    // per-wave P tile
  const int t = threadIdx.x, wid = t >> 6, lane = t & 63;
  const int r = lane & 15, g = lane >> 4;
  const int h = blockIdx.y;
  const int q0 = blockIdx.x * 64;
  bf16x8 qf[2];
  {
    const unsigned short* qp = Qb + ((size_t)h * Sq + q0 + wid * 16 + r) * 64 + g * 8;
    qf[0] = *(const bf16x8*)(qp);
    qf[1] = *(const bf16x8*)(qp + 32);
  }
  f32x4 o[4] = {};
  float mrun[4], lrun[4];
  #pragma unroll
  for (int j = 0; j < 4; j++){ mrun[j] = -__builtin_inff(); lrun[j] = 0.f; }
  const int nkv = Skv >> 6;
  for (int kv = 0; kv < nkv; ++kv){
    __syncthreads();
    #pragma unroll
    for (int i = 0; i < 2; i++){       // K tile: 64x64 bf16
      int idx = i * 256 + t;
      int row = idx >> 3, c8 = idx & 7;
      *(bf16x8*)(Ks + row * 72 + c8 * 8) =
          *(const bf16x8*)(Kb + ((size_t)h * Skv + kv * 64 + row) * 64 + c8 * 8);
    }
    #pragma unroll
    for (int i = 0; i < 16; i++){      // V tile transposed, fp32 -> bf16
      int e = i * 256 + t;
      int row = e >> 6, col = e & 63;
      Vt[col * 72 + row] = (short)f2bf(Vf[(size_t)(kv * 64 + row) * 1024 + h * 64 + col]);
    }
    __syncthreads();
    f32x4 sf[4];
    #pragma unroll
    for (int kj = 0; kj < 4; kj++){
      f32x4 a = {};
      #pragma unroll
      for (int kk = 0; kk < 2; kk++){
        bf16x8 kf = *(const bf16x8*)(Ks + (kj * 16 + r) * 72 + kk * 32 + g * 8);
        a = __builtin_amdgcn_mfma_f32_16x16x32_bf16(qf[kk], kf, a, 0, 0, 0);
      }
      sf[kj] = a * 0.125f;
    }
    #pragma unroll
    for (int j = 0; j < 4; j++){
      float tm = fmaxf(fmaxf(sf[0][j], sf[1][j]), fmaxf(sf[2][j], sf[3][j]));
      #pragma unroll
      for (int msk = 8; msk >= 1; msk >>= 1) tm = fmaxf(tm, __shfl_xor(tm, msk, 64));
      float mnew = fmaxf(mrun[j], tm);
      float corr = __expf(mrun[j] - mnew);
      mrun[j] = mnew;
      lrun[j] *= corr;
      #pragma unroll
      for (int dj = 0; dj < 4; dj++) o[dj][j] *= corr;
      float rsum = 0.f;
      #pragma unroll
      for (int kj = 0; kj < 4; kj++){
        float p = __expf(sf[kj][j] - mnew);
        rsum += p;
        Ps[(wid * 16 + g * 4 + j) * 72 + kj * 16 + r] = (short)f2bf(p);
      }
      #pragma unroll
      for (int msk = 8; msk >= 1; msk >>= 1) rsum += __shfl_xor(rsum, msk, 64);
      lrun[j] += rsum;
    }
    asm volatile("s_waitcnt lgkmcnt(0)" ::: "memory");
    #pragma unroll
    for (int kk = 0; kk < 2; kk++){
      bf16x8 pf = *(const bf16x8*)(Ps + (wid * 16 + r) * 72 + kk * 32 + g * 8);
      #pragma unroll
      for (int dj = 0; dj < 4; dj++){
        bf16x8 vfr = *(const bf16x8*)(Vt + (dj * 16 + r) * 72 + kk * 32 + g * 8);
        o[dj] = __builtin_amdgcn_mfma_f32_16x16x32_bf16(pf, vfr, o[dj], 0, 0, 0);
      }
    }
  }
  #pragma unroll
  for (int j = 0; j < 4; j++){
    float inv = 1.f / lrun[j];
    int qrow = q0 + wid * 16 + g * 4 + j;
    #pragma unroll
    for (int dj = 0; dj < 4; dj++)
      Out[(size_t)qrow * 1024 + h * 64 + dj * 16 + r] = f2bf(o[dj][j] * inv);
  }
}

extern "C" void kernel_launch(void* const* d_in, const int* in_sizes, int n_in,
                              void* d_out, int out_size, void* d_ws, size_t ws_size,
                              hipStream_t stream){
  (void)n_in; (void)out_size;
  const float* x   = (const float*)d_in[0];
  const float* emb = (const float*)d_in[1];
  const float* ctx = (const float*)d_in[2];
  int wb = 3, ri = 20;
  if (in_sizes[3] == 4096 * 64) { ri = 3; wb = 4; }   // signature order vs dict order
  const float* rope  = (const float*)d_in[ri];
  const float* sa_wq = (const float*)d_in[wb + 0];
  const float* sa_wk = (const float*)d_in[wb + 1];
  const float* sa_wv = (const float*)d_in[wb + 2];
  const float* sa_wo = (const float*)d_in[wb + 3];
  const float* sa_qn = (const float*)d_in[wb + 4];
  const float* sa_kn = (const float*)d_in[wb + 5];
  const float* ca_wq = (const float*)d_in[wb + 6];
  const float* ca_wk = (const float*)d_in[wb + 7];
  const float* ca_wv = (const float*)d_in[wb + 8];
  const float* ca_wo = (const float*)d_in[wb + 9];
  const float* ca_qn = (const float*)d_in[wb + 10];
  const float* ca_kn = (const float*)d_in[wb + 11];
  const float* w1    = (const float*)d_in[wb + 12];
  const float* w2    = (const float*)d_in[wb + 13];
  const float* msa   = (const float*)d_in[wb + 14];
  const float* mca   = (const float*)d_in[wb + 15];
  const float* mmlp  = (const float*)d_in[wb + 16];

  char* ws = (char*)d_ws;
  const size_t MB = 1u << 20;
  if (ws_size < 114 * MB) return;
  unsigned short* wq_sa = (unsigned short*)(ws + 0 * MB);
  unsigned short* wk_sa = (unsigned short*)(ws + 2 * MB);
  unsigned short* wv_sa = (unsigned short*)(ws + 4 * MB);
  unsigned short* wo_sa = (unsigned short*)(ws + 6 * MB);
  unsigned short* wq_ca = (unsigned short*)(ws + 8 * MB);
  unsigned short* wk_ca = (unsigned short*)(ws + 10 * MB);
  unsigned short* wv_ca = (unsigned short*)(ws + 12 * MB);
  unsigned short* wo_ca = (unsigned short*)(ws + 14 * MB);
  unsigned short* w1bf  = (unsigned short*)(ws + 16 * MB);
  unsigned short* w2bf  = (unsigned short*)(ws + 24 * MB);
  unsigned short* ctxbf = (unsigned short*)(ws + 32 * MB);
  float*          modv  = (float*)(ws + 33 * MB);
  unsigned short* hbf   = (unsigned short*)(ws + 34 * MB);
  unsigned short* qbf   = (unsigned short*)(ws + 42 * MB);
  unsigned short* kbf   = (unsigned short*)(ws + 50 * MB);
  unsigned short* aobf  = (unsigned short*)(ws + 58 * MB);
  float*          qf32  = (float*)(ws + 66 * MB);
  float*          kf32  = (float*)(ws + 82 * MB);
  float*          vf32  = (float*)(ws + 98 * MB);
  unsigned short* midbf = (unsigned short*)(ws + 66 * MB);  // aliases qkv scratch (MLP phase only)
  float* xcur = (float*)d_out;

  hipMemcpyAsync(d_out, x, (size_t)4096 * 1024 * 4, hipMemcpyDeviceToDevice, stream);

  auto cast = [&](const float* src, unsigned short* dst, int n){
    cast_kernel<<<(n / 4 + 255) / 256, 256, 0, stream>>>(src, dst, n / 4);
  };
  cast(sa_wq, wq_sa, 1024 * 1024);
  cast(sa_wk, wk_sa, 1024 * 1024);
  cast(sa_wv, wv_sa, 1024 * 1024);
  cast(sa_wo, wo_sa, 1024 * 1024);
  cast(ca_wq, wq_ca, 1024 * 1024);
  cast(ca_wk, wk_ca, 1024 * 1024);
  cast(ca_wv, wv_ca, 1024 * 1024);
  cast(ca_wo, wo_ca, 1024 * 1024);
  cast(w1, w1bf, 4096 * 1024);
  cast(w2, w2bf, 4096 * 1024);
  cast(ctx, ctxbf, 512 * 1024);
  modulation_kernel<<<2304, 256, 0, stream>>>(emb, msa, mca, mmlp, modv);

  // ---- self attention ----
  ln_mod_kernel<<<4096, 256, 0, stream>>>(xcur, modv + 0 * 3072, hbf);
  gemm_bt_kernel<0><<<dim3(8, 32), 256, 0, stream>>>(hbf, wq_sa, 4096, 1024, 1024, qf32, nullptr, nullptr, nullptr);
  gemm_bt_kernel<0><<<dim3(8, 32), 256, 0, stream>>>(hbf, wk_sa, 4096, 1024, 1024, kf32, nullptr, nullptr, nullptr);
  gemm_bt_kernel<0><<<dim3(8, 32), 256, 0, stream>>>(hbf, wv_sa, 4096, 1024, 1024, vf32, nullptr, nullptr, nullptr);
  qk_post_kernel<1><<<16384, 256, 0, stream>>>(qf32, sa_qn, rope, qbf, 4096);
  qk_post_kernel<1><<<16384, 256, 0, stream>>>(kf32, sa_kn, rope, kbf, 4096);
  attn_kernel<<<dim3(64, 16), 256, 0, stream>>>(qbf, kbf, vf32, aobf, 4096, 4096);
  gemm_bt_kernel<3><<<dim3(8, 32), 256, 0, stream>>>(aobf, wo_sa, 4096, 1024, 1024, xcur, nullptr, xcur, modv + 0 * 3072 + 2048);

  // ---- cross attention ----
  ln_mod_kernel<<<4096, 256, 0, stream>>>(xcur, modv + 1 * 3072, hbf);
  gemm_bt_kernel<0><<<dim3(8, 32), 256, 0, stream>>>(hbf, wq_ca, 4096, 1024, 1024, qf32, nullptr, nullptr, nullptr);
  gemm_bt_kernel<0><<<dim3(8, 4), 256, 0, stream>>>(ctxbf, wk_ca, 512, 1024, 1024, kf32, nullptr, nullptr, nullptr);
  gemm_bt_kernel<0><<<dim3(8, 4), 256, 0, stream>>>(ctxbf, wv_ca, 512, 1024, 1024, vf32, nullptr, nullptr, nullptr);
  qk_post_kernel<0><<<16384, 256, 0, stream>>>(qf32, ca_qn, nullptr, qbf, 4096);
  qk_post_kernel<0><<<2048, 256, 0, stream>>>(kf32, ca_kn, nullptr, kbf, 512);
  attn_kernel<<<dim3(64, 16), 256, 0, stream>>>(qbf, kbf, vf32, aobf, 4096, 512);
  gemm_bt_kernel<3><<<dim3(8, 32), 256, 0, stream>>>(aobf, wo_ca, 4096, 1024, 1024, xcur, nullptr, xcur, modv + 1 * 3072 + 2048);

  // ---- mlp ----
  ln_mod_kernel<<<4096, 256, 0, stream>>>(xcur, modv + 2 * 3072, hbf);
  gemm_bt_kernel<2><<<dim3(32, 32), 256, 0, stream>>>(hbf, w1bf, 4096, 4096, 1024, nullptr, midbf, nullptr, nullptr);
  gemm_bt_kernel<3><<<dim3(8, 32), 256, 0, stream>>>(midbf, w2bf, 4096, 1024, 4096, xcur, nullptr, xcur, modv + 2 * 3072 + 2048);
}

// Round 2
// 698.899 us; speedup vs baseline: 1.1079x; 1.1079x over previous
//
#include <hip/hip_runtime.h>
#include <hip/hip_bf16.h>

typedef __attribute__((ext_vector_type(8))) __bf16 bf16x8;
typedef __attribute__((ext_vector_type(4))) float f32x4;
typedef __attribute__((ext_vector_type(4))) unsigned short us4;

__device__ __forceinline__ unsigned short f2bf(float f){
  union { float f; unsigned int u; } a; a.f = f;
  unsigned int r = 0x7fffu + ((a.u >> 16) & 1u);
  return (unsigned short)((a.u + r) >> 16);
}

__device__ __forceinline__ void gload_lds16(const unsigned short* g, void* l){
  __builtin_amdgcn_global_load_lds(
      (const __attribute__((address_space(1))) void*)g,
      (__attribute__((address_space(3))) void*)l, 16, 0, 0);
}

// ---------------- cast fp32 -> bf16 (vector4) ----------------
__global__ __launch_bounds__(256) void cast_kernel(const float* __restrict__ in,
                                                   unsigned short* __restrict__ out, int n4){
  int i = blockIdx.x * 256 + threadIdx.x;
  if (i >= n4) return;
  float4 v = ((const float4*)in)[i];
  us4 o; o.x = f2bf(v.x); o.y = f2bf(v.y); o.z = f2bf(v.z); o.w = f2bf(v.w);
  ((us4*)out)[i] = o;
}

// ---------------- modulation: y = silu(emb) @ w.T (3 matrices of 3072x1024) ----------------
__global__ __launch_bounds__(256) void modulation_kernel(const float* __restrict__ emb,
    const float* __restrict__ w0, const float* __restrict__ w1, const float* __restrict__ w2,
    float* __restrict__ out){
  int gw = blockIdx.x * 4 + (threadIdx.x >> 6);
  int lane = threadIdx.x & 63;
  int mat = gw / 3072, row = gw % 3072;
  const float* w = (mat == 0) ? w0 : (mat == 1 ? w1 : w2);
  float acc = 0.f;
  for (int i = lane; i < 1024; i += 64){
    float e = emb[i];
    float s = e / (1.f + expf(-e));
    acc += s * w[row * 1024 + i];
  }
  #pragma unroll
  for (int m = 32; m >= 1; m >>= 1) acc += __shfl_xor(acc, m, 64);
  if (lane == 0) out[mat * 3072 + row] = acc;
}

// ---------------- layernorm * (1+scale) + shift -> bf16 ----------------
__global__ __launch_bounds__(256) void ln_mod_kernel(const float* __restrict__ x,
    const float* __restrict__ mod, unsigned short* __restrict__ h){
  int row = blockIdx.x, t = threadIdx.x;
  const float* xr = x + (size_t)row * 1024;
  float4 v = ((const float4*)xr)[t];
  float s = v.x + v.y + v.z + v.w;
  #pragma unroll
  for (int m = 32; m >= 1; m >>= 1) s += __shfl_xor(s, m, 64);
  __shared__ float red[4], red2[4];
  int wid = t >> 6, lane = t & 63;
  if (lane == 0) red[wid] = s;
  __syncthreads();
  float mean = (red[0] + red[1] + red[2] + red[3]) * (1.f / 1024.f);
  float dx = v.x - mean, dy = v.y - mean, dz = v.z - mean, dw = v.w - mean;
  float s2 = dx*dx + dy*dy + dz*dz + dw*dw;
  #pragma unroll
  for (int m = 32; m >= 1; m >>= 1) s2 += __shfl_xor(s2, m, 64);
  if (lane == 0) red2[wid] = s2;
  __syncthreads();
  float var = (red2[0] + red2[1] + red2[2] + red2[3]) * (1.f / 1024.f);
  float rs = rsqrtf(var + 1e-6f);
  int c = t * 4;
  us4 o;
  o.x = f2bf(dx * rs * (1.f + mod[1024 + c    ]) + mod[c    ]);
  o.y = f2bf(dy * rs * (1.f + mod[1024 + c + 1]) + mod[c + 1]);
  o.z = f2bf(dz * rs * (1.f + mod[1024 + c + 2]) + mod[c + 2]);
  o.w = f2bf(dw * rs * (1.f + mod[1024 + c + 3]) + mod[c + 3]);
  ((us4*)(h + (size_t)row * 1024))[t] = o;
}

// ---------------- rmsnorm (*nw) + optional rope, fp32 [S][16][64] -> bf16 [16][S][64] ----------------
template<int ROPE>
__global__ __launch_bounds__(256) void qk_post_kernel(const float* __restrict__ qin,
    const float* __restrict__ nw, const float* __restrict__ rope,
    unsigned short* __restrict__ qout, int S){
  int gw = blockIdx.x * 4 + (threadIdx.x >> 6);
  int lane = threadIdx.x & 63;
  int s = gw >> 4, h = gw & 15;
  float v = qin[(size_t)s * 1024 + h * 64 + lane];
  float ss = v * v;
  #pragma unroll
  for (int m = 32; m >= 1; m >>= 1) ss += __shfl_xor(ss, m, 64);
  float val = v * rsqrtf(ss * (1.f / 64.f) + 1e-6f) * nw[lane];
  if (ROPE){
    float partner = __shfl_xor(val, 32, 64);
    float cs = rope[s * 64 + (lane & 31)];
    float sn = rope[s * 64 + 32 + (lane & 31)];
    val = (lane < 32) ? (val * cs - partner * sn) : (val * cs + partner * sn);
  }
  qout[((size_t)h * S + s) * 64 + lane] = f2bf(val);
}

// ---------------- V transpose: fp32 [S][16][64] -> bf16 [16][64][S] ----------------
__global__ __launch_bounds__(256) void vt_kernel(const float* __restrict__ Vf,
    unsigned short* __restrict__ Vt, int S){
  int stile = blockIdx.x, h = blockIdx.y;
  __shared__ unsigned short tile[64 * 66];
  int t = threadIdx.x;
  #pragma unroll
  for (int i = 0; i < 16; i++){
    int e = i * 256 + t;
    int srow = e >> 6, d = e & 63;
    tile[d * 66 + srow] = f2bf(Vf[(size_t)(stile * 64 + srow) * 1024 + h * 64 + d]);
  }
  __syncthreads();
  #pragma unroll
  for (int i = 0; i < 16; i++){
    int e = i * 256 + t;
    int d = e >> 6, scol = e & 63;
    Vt[((size_t)h * 64 + d) * S + stile * 64 + scol] = tile[d * 66 + scol];
  }
}

// ---------------- GEMM: C[M,N] = A[M,K](bf16) * W[N,K](bf16)^T, fp32 acc ----------------
template<int EPI>
__global__ __launch_bounds__(256) void gemm_bt_kernel(
    const unsigned short* __restrict__ A, const unsigned short* __restrict__ W,
    int M, int N, int K,
    float* __restrict__ outF, unsigned short* __restrict__ outB,
    const float* __restrict__ resid, const float* __restrict__ gate){
  __shared__ short As[128 * 64];
  __shared__ short Bs[128 * 64];
  const int t = threadIdx.x, wid = t >> 6, lane = t & 63;
  const int r = lane & 15, g = lane >> 4;
  const int brow = blockIdx.y * 128, bcol = blockIdx.x * 128;
  const int wr = wid >> 1, wc = wid & 1;
  f32x4 acc[4][4] = {};
  const int nkt = K >> 6;
  for (int kt = 0; kt < nkt; ++kt){
    const int k0 = kt << 6;
    #pragma unroll
    for (int i = 0; i < 4; i++){
      int chunk = wid * 4 + i;
      int rowi = chunk * 8 + (lane >> 3);
      int lce = ((lane & 7) * 8) ^ ((rowi & 7) << 3);
      gload_lds16(A + (size_t)(brow + rowi) * K + k0 + lce, (void*)(As + chunk * 512));
      gload_lds16(W + (size_t)(bcol + rowi) * K + k0 + lce, (void*)(Bs + chunk * 512));
    }
    __syncthreads();
    #pragma unroll
    for (int kk = 0; kk < 2; kk++){
      bf16x8 af[4], bfr[4];
      #pragma unroll
      for (int m = 0; m < 4; m++){
        int ar = wr * 64 + m * 16 + r;
        af[m] = *(const bf16x8*)(As + ar * 64 + ((kk * 32 + g * 8) ^ ((ar & 7) << 3)));
      }
      #pragma unroll
      for (int n = 0; n < 4; n++){
        int br = wc * 64 + n * 16 + r;
        bfr[n] = *(const bf16x8*)(Bs + br * 64 + ((kk * 32 + g * 8) ^ ((br & 7) << 3)));
      }
      #pragma unroll
      for (int m = 0; m < 4; m++)
        #pragma unroll
        for (int n = 0; n < 4; n++)
          acc[m][n] = __builtin_amdgcn_mfma_f32_16x16x32_bf16(af[m], bfr[n], acc[m][n], 0, 0, 0);
    }
    __syncthreads();
  }
  #pragma unroll
  for (int m = 0; m < 4; m++){
    #pragma unroll
    for (int n = 0; n < 4; n++){
      int col = bcol + wc * 64 + n * 16 + r;
      #pragma unroll
      for (int j = 0; j < 4; j++){
        int rowj = brow + wr * 64 + m * 16 + g * 4 + j;
        float v = acc[m][n][j];
        if (EPI == 0){
          outF[(size_t)rowj * N + col] = v;
        } else if (EPI == 2){
          float gl = 0.5f * v * (1.f + erff(v * 0.70710678118654752f));
          outB[(size_t)rowj * N + col] = f2bf(gl);
        } else {
          outF[(size_t)rowj * N + col] = resid[(size_t)rowj * N + col] + gate[col] * v;
        }
      }
    }
  }
}

// ---------------- flash attention, barrier-free ----------------
// Q: bf16 [16][Sq][64], K: bf16 [16][Skv][64], Vt: bf16 [16][64][Skv], Out: bf16 [Sq][1024]
// 4 waves/block, 32 q-rows/wave (2 MFMA tiles), KVBLK=64.
// K/V fragments read directly from global (L2-resident via XCD-aware head placement).
__global__ __launch_bounds__(256) void attn_kernel(
    const unsigned short* __restrict__ Qb, const unsigned short* __restrict__ Kb,
    const unsigned short* __restrict__ Vt, unsigned short* __restrict__ Out,
    int Sq, int Skv){
  __shared__ short Ps[4][32 * 72];
  const int t = threadIdx.x, wid = t >> 6, lane = t & 63;
  const int r = lane & 15, g = lane >> 4;
  // XCD swizzle: 512 blocks; bid&7 = XCD (empirical round-robin). 2 heads/XCD ->
  // per-XCD K+V working set = 2 MB, fits 4 MB L2.
  const int bid = blockIdx.x;
  const int slot = bid >> 3;
  const int h = (bid & 7) * 2 + (slot >> 5);
  const int qblk = slot & 31;
  const int qbase = qblk * 128 + wid * 32;

  bf16x8 qf[2][2];
  #pragma unroll
  for (int tile = 0; tile < 2; tile++){
    const unsigned short* qp = Qb + ((size_t)h * Sq + qbase + tile * 16 + r) * 64 + g * 8;
    qf[tile][0] = *(const bf16x8*)qp;
    qf[tile][1] = *(const bf16x8*)(qp + 32);
  }
  f32x4 o[2][4] = {};
  float mrun[2][4], lrun[2][4];
  #pragma unroll
  for (int tile = 0; tile < 2; tile++)
    #pragma unroll
    for (int j = 0; j < 4; j++){ mrun[tile][j] = -__builtin_inff(); lrun[tile][j] = 0.f; }

  for (int kv = 0; kv < Skv; kv += 64){
    // ---- QK^T: K fragments direct from global ----
    const unsigned short* kp = Kb + ((size_t)h * Skv + kv + r) * 64 + g * 8;
    f32x4 sf[2][4];
    #pragma unroll
    for (int kj = 0; kj < 4; kj++){
      bf16x8 k0 = *(const bf16x8*)(kp + kj * 1024);
      bf16x8 k1 = *(const bf16x8*)(kp + kj * 1024 + 32);
      f32x4 a0 = {}, a1 = {};
      a0 = __builtin_amdgcn_mfma_f32_16x16x32_bf16(qf[0][0], k0, a0, 0, 0, 0);
      a0 = __builtin_amdgcn_mfma_f32_16x16x32_bf16(qf[0][1], k1, a0, 0, 0, 0);
      a1 = __builtin_amdgcn_mfma_f32_16x16x32_bf16(qf[1][0], k0, a1, 0, 0, 0);
      a1 = __builtin_amdgcn_mfma_f32_16x16x32_bf16(qf[1][1], k1, a1, 0, 0, 0);
      sf[0][kj] = a0 * 0.125f;
      sf[1][kj] = a1 * 0.125f;
    }
    // ---- V fragments: issue early so latency hides under softmax ----
    bf16x8 vf[2][4];
    const unsigned short* vp = Vt + ((size_t)h * 64 + r) * Skv + kv + g * 8;
    #pragma unroll
    for (int dj = 0; dj < 4; dj++){
      vf[0][dj] = *(const bf16x8*)(vp + (size_t)dj * 16 * Skv);
      vf[1][dj] = *(const bf16x8*)(vp + (size_t)dj * 16 * Skv + 32);
    }
    // ---- online softmax (defer-rescale, THR=8) ----
    #pragma unroll
    for (int tile = 0; tile < 2; tile++){
      float tm[4];
      int need = 0;
      #pragma unroll
      for (int j = 0; j < 4; j++){
        float m0 = fmaxf(fmaxf(sf[tile][0][j], sf[tile][1][j]),
                         fmaxf(sf[tile][2][j], sf[tile][3][j]));
        #pragma unroll
        for (int msk = 8; msk >= 1; msk >>= 1) m0 = fmaxf(m0, __shfl_xor(m0, msk, 64));
        tm[j] = m0;
        need |= (m0 > mrun[tile][j] + 8.f) ? 1 : 0;
      }
      if (__any(need)){
        #pragma unroll
        for (int j = 0; j < 4; j++){
          float mnew = fmaxf(mrun[tile][j], tm[j]);
          float corr = __expf(mrun[tile][j] - mnew);
          mrun[tile][j] = mnew;
          lrun[tile][j] *= corr;
          #pragma unroll
          for (int dj = 0; dj < 4; dj++) o[tile][dj][j] *= corr;
        }
      }
      #pragma unroll
      for (int j = 0; j < 4; j++){
        float rsum = 0.f;
        #pragma unroll
        for (int kj = 0; kj < 4; kj++){
          float p = __expf(sf[tile][kj][j] - mrun[tile][j]);
          rsum += p;
          Ps[wid][(tile * 16 + g * 4 + j) * 72 + kj * 16 + r] = (short)f2bf(p);
        }
        #pragma unroll
        for (int msk = 8; msk >= 1; msk >>= 1) rsum += __shfl_xor(rsum, msk, 64);
        lrun[tile][j] += rsum;
      }
    }
    asm volatile("s_waitcnt lgkmcnt(0)" ::: "memory");
    // ---- PV ----
    __builtin_amdgcn_s_setprio(1);
    #pragma unroll
    for (int tile = 0; tile < 2; tile++){
      bf16x8 pf0 = *(const bf16x8*)(&Ps[wid][(tile * 16 + r) * 72 + g * 8]);
      bf16x8 pf1 = *(const bf16x8*)(&Ps[wid][(tile * 16 + r) * 72 + 32 + g * 8]);
      #pragma unroll
      for (int dj = 0; dj < 4; dj++){
        o[tile][dj] = __builtin_amdgcn_mfma_f32_16x16x32_bf16(pf0, vf[0][dj], o[tile][dj], 0, 0, 0);
        o[tile][dj] = __builtin_amdgcn_mfma_f32_16x16x32_bf16(pf1, vf[1][dj], o[tile][dj], 0, 0, 0);
      }
    }
    __builtin_amdgcn_s_setprio(0);
  }
  #pragma unroll
  for (int tile = 0; tile < 2; tile++){
    #pragma unroll
    for (int j = 0; j < 4; j++){
      float inv = 1.f / lrun[tile][j];
      int qrow = qbase + tile * 16 + g * 4 + j;
      #pragma unroll
      for (int dj = 0; dj < 4; dj++)
        Out[(size_t)qrow * 1024 + h * 64 + dj * 16 + r] = f2bf(o[tile][dj][j] * inv);
    }
  }
}

extern "C" void kernel_launch(void* const* d_in, const int* in_sizes, int n_in,
                              void* d_out, int out_size, void* d_ws, size_t ws_size,
                              hipStream_t stream){
  (void)n_in; (void)out_size;
  const float* x   = (const float*)d_in[0];
  const float* emb = (const float*)d_in[1];
  const float* ctx = (const float*)d_in[2];
  int wb = 3, ri = 20;
  if (in_sizes[3] == 4096 * 64) { ri = 3; wb = 4; }
  const float* rope  = (const float*)d_in[ri];
  const float* sa_wq = (const float*)d_in[wb + 0];
  const float* sa_wk = (const float*)d_in[wb + 1];
  const float* sa_wv = (const float*)d_in[wb + 2];
  const float* sa_wo = (const float*)d_in[wb + 3];
  const float* sa_qn = (const float*)d_in[wb + 4];
  const float* sa_kn = (const float*)d_in[wb + 5];
  const float* ca_wq = (const float*)d_in[wb + 6];
  const float* ca_wk = (const float*)d_in[wb + 7];
  const float* ca_wv = (const float*)d_in[wb + 8];
  const float* ca_wo = (const float*)d_in[wb + 9];
  const float* ca_qn = (const float*)d_in[wb + 10];
  const float* ca_kn = (const float*)d_in[wb + 11];
  const float* w1    = (const float*)d_in[wb + 12];
  const float* w2    = (const float*)d_in[wb + 13];
  const float* msa   = (const float*)d_in[wb + 14];
  const float* mca   = (const float*)d_in[wb + 15];
  const float* mmlp  = (const float*)d_in[wb + 16];

  char* ws = (char*)d_ws;
  const size_t MB = 1u << 20;
  if (ws_size < 114 * MB) return;
  unsigned short* wq_sa = (unsigned short*)(ws + 0 * MB);
  unsigned short* wk_sa = (unsigned short*)(ws + 2 * MB);
  unsigned short* wv_sa = (unsigned short*)(ws + 4 * MB);
  unsigned short* wo_sa = (unsigned short*)(ws + 6 * MB);
  unsigned short* wq_ca = (unsigned short*)(ws + 8 * MB);
  unsigned short* wk_ca = (unsigned short*)(ws + 10 * MB);
  unsigned short* wv_ca = (unsigned short*)(ws + 12 * MB);
  unsigned short* wo_ca = (unsigned short*)(ws + 14 * MB);
  unsigned short* w1bf  = (unsigned short*)(ws + 16 * MB);
  unsigned short* w2bf  = (unsigned short*)(ws + 24 * MB);
  unsigned short* ctxbf = (unsigned short*)(ws + 32 * MB);
  float*          modv  = (float*)(ws + 33 * MB);
  unsigned short* hbf   = (unsigned short*)(ws + 34 * MB);
  unsigned short* qbf   = (unsigned short*)(ws + 42 * MB);
  unsigned short* kbf   = (unsigned short*)(ws + 50 * MB);
  unsigned short* aobf  = (unsigned short*)(ws + 58 * MB);
  float*          qf32  = (float*)(ws + 66 * MB);
  float*          kf32  = (float*)(ws + 82 * MB);
  float*          vf32  = (float*)(ws + 98 * MB);
  unsigned short* vtb   = (unsigned short*)(ws + 82 * MB);  // aliases kf32: only valid AFTER qk_post(k)
  unsigned short* midbf = (unsigned short*)(ws + 66 * MB);  // aliases q/k scratch (MLP phase only)
  float* xcur = (float*)d_out;

  hipMemcpyAsync(d_out, x, (size_t)4096 * 1024 * 4, hipMemcpyDeviceToDevice, stream);

  auto cast = [&](const float* src, unsigned short* dst, int n){
    cast_kernel<<<(n / 4 + 255) / 256, 256, 0, stream>>>(src, dst, n / 4);
  };
  cast(sa_wq, wq_sa, 1024 * 1024);
  cast(sa_wk, wk_sa, 1024 * 1024);
  cast(sa_wv, wv_sa, 1024 * 1024);
  cast(sa_wo, wo_sa, 1024 * 1024);
  cast(ca_wq, wq_ca, 1024 * 1024);
  cast(ca_wk, wk_ca, 1024 * 1024);
  cast(ca_wv, wv_ca, 1024 * 1024);
  cast(ca_wo, wo_ca, 1024 * 1024);
  cast(w1, w1bf, 4096 * 1024);
  cast(w2, w2bf, 4096 * 1024);
  cast(ctx, ctxbf, 512 * 1024);
  modulation_kernel<<<2304, 256, 0, stream>>>(emb, msa, mca, mmlp, modv);

  // ---- self attention ----
  ln_mod_kernel<<<4096, 256, 0, stream>>>(xcur, modv + 0 * 3072, hbf);
  gemm_bt_kernel<0><<<dim3(8, 32), 256, 0, stream>>>(hbf, wq_sa, 4096, 1024, 1024, qf32, nullptr, nullptr, nullptr);
  gemm_bt_kernel<0><<<dim3(8, 32), 256, 0, stream>>>(hbf, wk_sa, 4096, 1024, 1024, kf32, nullptr, nullptr, nullptr);
  gemm_bt_kernel<0><<<dim3(8, 32), 256, 0, stream>>>(hbf, wv_sa, 4096, 1024, 1024, vf32, nullptr, nullptr, nullptr);
  qk_post_kernel<1><<<16384, 256, 0, stream>>>(qf32, sa_qn, rope, qbf, 4096);
  qk_post_kernel<1><<<16384, 256, 0, stream>>>(kf32, sa_kn, rope, kbf, 4096);
  vt_kernel<<<dim3(64, 16), 256, 0, stream>>>(vf32, vtb, 4096);   // after qk_post(k): overwrites kf32
  attn_kernel<<<512, 256, 0, stream>>>(qbf, kbf, vtb, aobf, 4096, 4096);
  gemm_bt_kernel<3><<<dim3(8, 32), 256, 0, stream>>>(aobf, wo_sa, 4096, 1024, 1024, xcur, nullptr, xcur, modv + 0 * 3072 + 2048);

  // ---- cross attention ----
  ln_mod_kernel<<<4096, 256, 0, stream>>>(xcur, modv + 1 * 3072, hbf);
  gemm_bt_kernel<0><<<dim3(8, 32), 256, 0, stream>>>(hbf, wq_ca, 4096, 1024, 1024, qf32, nullptr, nullptr, nullptr);
  gemm_bt_kernel<0><<<dim3(8, 4), 256, 0, stream>>>(ctxbf, wk_ca, 512, 1024, 1024, kf32, nullptr, nullptr, nullptr);
  gemm_bt_kernel<0><<<dim3(8, 4), 256, 0, stream>>>(ctxbf, wv_ca, 512, 1024, 1024, vf32, nullptr, nullptr, nullptr);
  qk_post_kernel<0><<<16384, 256, 0, stream>>>(qf32, ca_qn, nullptr, qbf, 4096);
  qk_post_kernel<0><<<2048, 256, 0, stream>>>(kf32, ca_kn, nullptr, kbf, 512);
  vt_kernel<<<dim3(8, 16), 256, 0, stream>>>(vf32, vtb, 512);     // after qk_post(k)
  attn_kernel<<<512, 256, 0, stream>>>(qbf, kbf, vtb, aobf, 4096, 512);
  gemm_bt_kernel<3><<<dim3(8, 32), 256, 0, stream>>>(aobf, wo_ca, 4096, 1024, 1024, xcur, nullptr, xcur, modv + 1 * 3072 + 2048);

  // ---- mlp ----
  ln_mod_kernel<<<4096, 256, 0, stream>>>(xcur, modv + 2 * 3072, hbf);
  gemm_bt_kernel<2><<<dim3(32, 32), 256, 0, stream>>>(hbf, w1bf, 4096, 4096, 1024, nullptr, midbf, nullptr, nullptr);
  gemm_bt_kernel<3><<<dim3(8, 32), 256, 0, stream>>>(midbf, w2bf, 4096, 1024, 4096, xcur, nullptr, xcur, modv + 2 * 3072 + 2048);
}